// Round 15
// baseline (3385.610 us; speedup 1.0000x reference)
//
#include <hip/hip_runtime.h>
#include <math.h>

#define BB 4
#define NN 20000
#define NE 320000
#define WW 256
#define SS 64
#define NH 8
#define HD 32
#define NF 1024
#define NL 4
#define GEPS 1e-6f

typedef __attribute__((ext_vector_type(8))) short short8v;
typedef __attribute__((ext_vector_type(4))) float f32x4;

static __device__ __forceinline__ short f2bf(float x){
  union { float f; unsigned u; } v; v.f = x;
  unsigned r = v.u + 0x7fffu + ((v.u >> 16) & 1u);
  return (short)(r >> 16);
}
static __device__ __forceinline__ float bfu_lo(unsigned u){
  union { unsigned u; float f; } v; v.u = u << 16; return v.f;
}
static __device__ __forceinline__ float bfu_hi(unsigned u){
  union { unsigned u; float f; } v; v.u = u & 0xffff0000u; return v.f;
}
static __device__ __forceinline__ float gelu_f(float x){
  return 0.5f*x*(1.0f + erff(x*0.70710678118654752f));
}

#define GLOAD16(gsrc, ldst) \
  __builtin_amdgcn_global_load_lds( \
      (const __attribute__((address_space(1))) void*)(gsrc), \
      (__attribute__((address_space(3))) void*)(ldst), 16, 0, 0)

// ---------------------------------------------------------------- embed
__global__ __launch_bounds__(256) void k_embed(
    const float* __restrict__ fields, const float* __restrict__ coords,
    const float* __restrict__ t_norm, const float* __restrict__ freq,
    const float* __restrict__ omega, const float* __restrict__ in_w,
    const float* __restrict__ in_b, float* __restrict__ h)
{
  __shared__ float inv[16][28];
  __shared__ float temb[8];
  const int t = threadIdx.x;
  const size_t tok0 = (size_t)blockIdx.x * 16;
  const int b = (int)(tok0 / NN);
  if (t < 8) {
    int f = t & 3;
    float ang = t_norm[b] * 1000.0f * omega[f];
    temb[t] = (t < 4) ? sinf(ang) : cosf(ang);
  }
  if (t < 128) {
    int tok = t >> 3, f = t & 7;
    size_t n = tok0 + tok;
    float c0 = coords[n*2+0], c1 = coords[n*2+1];
    float sp = 6.283185307179586f * (c0*freq[f] + c1*freq[8+f]);
    inv[tok][4+f]  = sinf(sp);
    inv[tok][12+f] = cosf(sp);
  } else if (t < 192) {
    int idx = t - 128; int tok = idx >> 2, i = idx & 3;
    inv[tok][i] = fields[(tok0+tok)*4 + i];
  }
  __syncthreads();
  if (t < 128) {
    int tok = t >> 3, f = t & 7;
    inv[tok][20+f] = temb[f];
  }
  __syncthreads();
  float acc[16];
  float bias = in_b[t];
  #pragma unroll
  for (int i = 0; i < 16; i++) acc[i] = bias;
  #pragma unroll 4
  for (int k = 0; k < 28; k++) {
    float w = in_w[k*WW + t];
    #pragma unroll
    for (int i = 0; i < 16; i++) acc[i] += inv[i][k]*w;
  }
  #pragma unroll
  for (int i = 0; i < 16; i++) h[(tok0+i)*WW + t] = acc[i];
}

// ------------------------------------------------- LN1 + slice weights
__global__ __launch_bounds__(256) void k_lnw(
    const float* __restrict__ h, const float* __restrict__ lnw,
    const float* __restrict__ lnb, const float* __restrict__ sw,
    const float* __restrict__ sb, float* __restrict__ wts,
    short* __restrict__ wtsb, float* __restrict__ mu_rstd)
{
  __shared__ float hn[16][WW];
  __shared__ float ps[16][16], pq[16][16];
  __shared__ float mus[16], rss[16];
  const int t = threadIdx.x;
  const size_t tok0 = (size_t)blockIdx.x * 16;
  const int tok = t >> 4, seg = t & 15;
  {
    const float4* hp = (const float4*)(h + (tok0+tok)*WW + seg*16);
    float sum = 0.f, sq = 0.f;
    #pragma unroll
    for (int i = 0; i < 4; i++){
      float4 v = hp[i];
      sum += v.x+v.y+v.z+v.w;
      sq  += v.x*v.x+v.y*v.y+v.z*v.z+v.w*v.w;
      *((float4*)&hn[tok][seg*16 + i*4]) = v;
    }
    ps[tok][seg] = sum; pq[tok][seg] = sq;
  }
  __syncthreads();
  if (t < 16){
    float s0=0.f, q0=0.f;
    #pragma unroll
    for (int i = 0; i < 16; i++){ s0 += ps[t][i]; q0 += pq[t][i]; }
    float mu = s0*(1.0f/WW);
    float var = q0*(1.0f/WW) - mu*mu;
    float rs = rsqrtf(var + 1e-5f);
    mus[t] = mu; rss[t] = rs;
    mu_rstd[(tok0 + t)*2]     = mu;
    mu_rstd[(tok0 + t)*2 + 1] = rs;
  }
  __syncthreads();
  {
    float mu = mus[tok], rs = rss[tok];
    #pragma unroll
    for (int i = 0; i < 16; i++){
      int c = seg*16 + i;
      hn[tok][c] = (hn[tok][c]-mu)*rs*lnw[c] + lnb[c];
    }
  }
  __syncthreads();
  const int s = t & 63, tg = t >> 6;
  float acc[4];
  float bs = sb[s];
  #pragma unroll
  for (int i = 0; i < 4; i++) acc[i] = bs;
  for (int c4 = 0; c4 < 64; c4++){
    float w0 = sw[(c4*4+0)*SS + s];
    float w1 = sw[(c4*4+1)*SS + s];
    float w2 = sw[(c4*4+2)*SS + s];
    float w3 = sw[(c4*4+3)*SS + s];
    #pragma unroll
    for (int i = 0; i < 4; i++){
      float4 hv = *((const float4*)&hn[tg*4+i][c4*4]);
      acc[i] += hv.x*w0 + hv.y*w1 + hv.z*w2 + hv.w*w3;
    }
  }
  #pragma unroll
  for (int i = 0; i < 4; i++){
    float m = acc[i];
    #pragma unroll
    for (int off = 32; off > 0; off >>= 1) m = fmaxf(m, __shfl_xor(m, off));
    float e = expf(acc[i] - m);
    float ssum = e;
    #pragma unroll
    for (int off = 32; off > 0; off >>= 1) ssum += __shfl_xor(ssum, off);
    float wv = e/ssum;
    wts[(tok0 + tg*4 + i)*SS + s] = wv;
    wtsb[(tok0 + tg*4 + i)*SS + s] = f2bf(wv);
  }
}

// ------------------------------------------------- slices partial sums
__global__ __launch_bounds__(256) void k_slices(
    const float* __restrict__ h, const float* __restrict__ wts,
    const float* __restrict__ mu_rstd, const float* __restrict__ lnw,
    const float* __restrict__ lnb, float* __restrict__ sacc,
    float* __restrict__ wsum)
{
  __shared__ float wstage[16][SS];
  const int t = threadIdx.x;
  const int b = blockIdx.y;
  const int n0 = blockIdx.x * 128;
  const float lw = lnw[t], lb = lnb[t];
  float acc[SS];
  #pragma unroll
  for (int s = 0; s < SS; s++) acc[s] = 0.f;
  float wsl = 0.f;
  for (int it = 0; it < 8; it++){
    int nb = n0 + it*16;
    {
      int tk = t >> 4, s4 = (t & 15)*4;
      int n = nb + tk;
      float4 v = make_float4(0.f,0.f,0.f,0.f);
      if (n < NN) v = *((const float4*)(wts + ((size_t)b*NN + n)*SS + s4));
      *((float4*)&wstage[tk][s4]) = v;
    }
    __syncthreads();
    #pragma unroll 4
    for (int tk = 0; tk < 16; tk++){
      int n = nb + tk;
      if (n < NN){
        size_t g = (size_t)b*NN + n;
        float mu = mu_rstd[g*2], rsd = mu_rstd[g*2+1];
        float hv = h[g*WW + t];
        float hnv = (hv-mu)*rsd*lw + lb;
        #pragma unroll
        for (int s4 = 0; s4 < 16; s4++){
          float4 wv = *((const float4*)&wstage[tk][s4*4]);
          acc[s4*4+0] += wv.x*hnv;
          acc[s4*4+1] += wv.y*hnv;
          acc[s4*4+2] += wv.z*hnv;
          acc[s4*4+3] += wv.w*hnv;
        }
      }
    }
    if (t < SS){
      #pragma unroll
      for (int tk = 0; tk < 16; tk++) wsl += wstage[tk][t];
    }
    __syncthreads();
  }
  #pragma unroll
  for (int s = 0; s < SS; s++)
    atomicAdd(&sacc[((size_t)b*SS + s)*WW + t], acc[s]);
  if (t < SS) atomicAdd(&wsum[b*SS + t], wsl);
}

// ------------------------------------------------- gb edge accumulation (v3)
// 2000 blocks: per-wave serial chain halved (80 gather iterations).
#define GB_BLKS 2000
#define GB_PB   500
#define GB_EDG  (NE/GB_PB)    // 640
__global__ __launch_bounds__(256) void k_gb2(
    const short* __restrict__ wtsb, const int* __restrict__ adj,
    const float* __restrict__ vals, float* __restrict__ gb)
{
  __shared__ float gbw[SS*SS];
  const int t = threadIdx.x;
  const int bid = blockIdx.x;
  const int xcd = bid & 7;
  const int b = xcd >> 1;                        // batch -> XCD pair
  const int grp = (bid >> 3)*2 + (xcd & 1);      // 0..499 within batch
  const int e0 = grp * GB_EDG;
  const int w = t >> 6, l = t & 63;
  const int sg = l >> 3, tg = l & 7;
  #pragma unroll
  for (int i = 0; i < 16; i++) gbw[t + 256*i] = 0.f;
  __syncthreads();
  float acc[8][8];
  #pragma unroll
  for (int i = 0; i < 8; i++)
    #pragma unroll
    for (int u = 0; u < 8; u++) acc[i][u] = 0.f;
  const short* wb = wtsb + (size_t)b*NN*SS;
  for (int e = e0 + w; e < e0 + GB_EDG; e += 8){
    int row0 = adj[e],     col0 = adj[NE + e];
    int row1 = adj[e + 4], col1 = adj[NE + e + 4];
    float v0 = vals[e], v1 = vals[e + 4];
    uint4 ru0 = *(const uint4*)(wb + (size_t)row0*SS + sg*8);
    uint4 cu0 = *(const uint4*)(wb + (size_t)col0*SS + tg*8);
    uint4 ru1 = *(const uint4*)(wb + (size_t)row1*SS + sg*8);
    uint4 cu1 = *(const uint4*)(wb + (size_t)col1*SS + tg*8);
    float rr[8], cc[8];
    rr[0]=bfu_lo(ru0.x)*v0; rr[1]=bfu_hi(ru0.x)*v0;
    rr[2]=bfu_lo(ru0.y)*v0; rr[3]=bfu_hi(ru0.y)*v0;
    rr[4]=bfu_lo(ru0.z)*v0; rr[5]=bfu_hi(ru0.z)*v0;
    rr[6]=bfu_lo(ru0.w)*v0; rr[7]=bfu_hi(ru0.w)*v0;
    cc[0]=bfu_lo(cu0.x); cc[1]=bfu_hi(cu0.x);
    cc[2]=bfu_lo(cu0.y); cc[3]=bfu_hi(cu0.y);
    cc[4]=bfu_lo(cu0.z); cc[5]=bfu_hi(cu0.z);
    cc[6]=bfu_lo(cu0.w); cc[7]=bfu_hi(cu0.w);
    #pragma unroll
    for (int i = 0; i < 8; i++)
      #pragma unroll
      for (int u = 0; u < 8; u++) acc[i][u] += rr[i]*cc[u];
    rr[0]=bfu_lo(ru1.x)*v1; rr[1]=bfu_hi(ru1.x)*v1;
    rr[2]=bfu_lo(ru1.y)*v1; rr[3]=bfu_hi(ru1.y)*v1;
    rr[4]=bfu_lo(ru1.z)*v1; rr[5]=bfu_hi(ru1.z)*v1;
    rr[6]=bfu_lo(ru1.w)*v1; rr[7]=bfu_hi(ru1.w)*v1;
    cc[0]=bfu_lo(cu1.x); cc[1]=bfu_hi(cu1.x);
    cc[2]=bfu_lo(cu1.y); cc[3]=bfu_hi(cu1.y);
    cc[4]=bfu_lo(cu1.z); cc[5]=bfu_hi(cu1.z);
    cc[6]=bfu_lo(cu1.w); cc[7]=bfu_hi(cu1.w);
    #pragma unroll
    for (int i = 0; i < 8; i++)
      #pragma unroll
      for (int u = 0; u < 8; u++) acc[i][u] += rr[i]*cc[u];
  }
  #pragma unroll
  for (int i = 0; i < 8; i++)
    #pragma unroll
    for (int u = 0; u < 8; u++)
      atomicAdd(&gbw[(sg*8+i)*SS + tg*8 + u], acc[i][u]);
  __syncthreads();
  #pragma unroll
  for (int i = 0; i < 16; i++){
    int idx = t + 256*i;
    atomicAdd(&gb[(size_t)b*SS*SS + idx], gbw[idx]);
  }
}

// ------------------- attention per (head,b), with fused slices_fin + gbfin
__global__ __launch_bounds__(256) void k_attn(
    const float* __restrict__ sacc, const float* __restrict__ wsum,
    const float* __restrict__ gbin, const float* __restrict__ beta_raw,
    int layer,
    const float* __restrict__ qw, const float* __restrict__ qb,
    const float* __restrict__ kw, const float* __restrict__ kb,
    const float* __restrict__ vw, const float* __restrict__ vb,
    float* __restrict__ so)
{
  __shared__ float sl[SS][WW];          // 64 KB
  __shared__ float qh[SS][HD], kh[SS][HD], vh[SS][HD];   // 24 KB
  __shared__ float att[SS*SS];          // 16 KB (first used as gb scratch)
  __shared__ float gbl[SS*SS];          // 16 KB
  __shared__ float rws[SS], rs2[SS];
  const int t = threadIdx.x;
  const int hh = blockIdx.x, b = blockIdx.y;
  // phase A: load raw gb into att-scratch; slice normalizers
  #pragma unroll
  for (int i = 0; i < 16; i++)
    att[t + 256*i] = gbin[(size_t)b*SS*SS + t + 256*i];
  if (t < SS) rws[t] = 1.0f / fmaxf(wsum[b*SS + t], GEPS);
  __syncthreads();
  // phase B: symmetrize into gbl; load sl = sacc * rws[s]  (float4: 4096 x 16B)
  #pragma unroll
  for (int i = 0; i < 16; i++){
    int idx = t + 256*i; int r = idx >> 6, c = idx & 63;
    gbl[idx] = 0.5f*(att[idx] + att[c*SS + r]);
  }
  {
    const float4* sp4 = (const float4*)(sacc + (size_t)b*SS*WW);
    float4* sl4 = (float4*)&sl[0][0];
    #pragma unroll
    for (int i = 0; i < 16; i++){
      int idx = t + 256*i;            // 0..4095 float4s; 64 per row
      int s = idx >> 6;
      float r = rws[s];
      float4 v = sp4[idx];
      v.x *= r; v.y *= r; v.z *= r; v.w *= r;
      sl4[idx] = v;
    }
  }
  __syncthreads();
  // phase C: gb row sums
  if (t < SS){
    float sum = 0.f;
    for (int c = 0; c < SS; c++) sum += gbl[t*SS + c];
    rs2[t] = 1.0f / fmaxf(sum, GEPS);
  }
  __syncthreads();
  // phase D: finalize gbl = beta*log(...) in place
  {
    float beta = log1pf(expf(beta_raw[layer]));
    #pragma unroll
    for (int i = 0; i < 16; i++){
      int idx = t + 256*i; int r = idx >> 6;
      gbl[idx] = beta * logf(fmaxf(gbl[idx]*rs2[r], GEPS));
    }
  }
  // ---- QKV projection (reads sl); gbl writes become visible at the
  //      __syncthreads below, before any gbl read ----
  const int s = t >> 2, dq = t & 3, d0 = dq*8;
  float aq[8], ak[8], av[8];
  #pragma unroll
  for (int j = 0; j < 8; j++){
    aq[j] = qb[hh*HD + d0 + j];
    ak[j] = kb[hh*HD + d0 + j];
    av[j] = vb[hh*HD + d0 + j];
  }
  for (int c = 0; c < WW; c++){
    float sv = sl[s][c];
    const float4* q4 = (const float4*)(qw + (size_t)c*WW + hh*HD + d0);
    const float4* k4 = (const float4*)(kw + (size_t)c*WW + hh*HD + d0);
    const float4* v4 = (const float4*)(vw + (size_t)c*WW + hh*HD + d0);
    float4 qa = q4[0], qc = q4[1];
    float4 ka = k4[0], kc = k4[1];
    float4 va = v4[0], vc = v4[1];
    aq[0]+=sv*qa.x; aq[1]+=sv*qa.y; aq[2]+=sv*qa.z; aq[3]+=sv*qa.w;
    aq[4]+=sv*qc.x; aq[5]+=sv*qc.y; aq[6]+=sv*qc.z; aq[7]+=sv*qc.w;
    ak[0]+=sv*ka.x; ak[1]+=sv*ka.y; ak[2]+=sv*ka.z; ak[3]+=sv*ka.w;
    ak[4]+=sv*kc.x; ak[5]+=sv*kc.y; ak[6]+=sv*kc.z; ak[7]+=sv*kc.w;
    av[0]+=sv*va.x; av[1]+=sv*va.y; av[2]+=sv*va.z; av[3]+=sv*va.w;
    av[4]+=sv*vc.x; av[5]+=sv*vc.y; av[6]+=sv*vc.z; av[7]+=sv*vc.w;
  }
  *((float4*)&qh[s][d0])   = make_float4(aq[0],aq[1],aq[2],aq[3]);
  *((float4*)&qh[s][d0+4]) = make_float4(aq[4],aq[5],aq[6],aq[7]);
  *((float4*)&kh[s][d0])   = make_float4(ak[0],ak[1],ak[2],ak[3]);
  *((float4*)&kh[s][d0+4]) = make_float4(ak[4],ak[5],ak[6],ak[7]);
  *((float4*)&vh[s][d0])   = make_float4(av[0],av[1],av[2],av[3]);
  *((float4*)&vh[s][d0+4]) = make_float4(av[4],av[5],av[6],av[7]);
  __syncthreads();
  float qreg[HD];
  #pragma unroll
  for (int d4 = 0; d4 < 8; d4++){
    float4 qv = *((const float4*)&qh[s][d4*4]);
    qreg[d4*4+0]=qv.x; qreg[d4*4+1]=qv.y; qreg[d4*4+2]=qv.z; qreg[d4*4+3]=qv.w;
  }
  const int tc0 = dq*16;
  float lg[16];
  #pragma unroll
  for (int u = 0; u < 16; u++){
    float a = 0.f;
    #pragma unroll
    for (int d4 = 0; d4 < 8; d4++){
      float4 kv = *((const float4*)&kh[tc0+u][d4*4]);
      a += qreg[d4*4+0]*kv.x + qreg[d4*4+1]*kv.y + qreg[d4*4+2]*kv.z + qreg[d4*4+3]*kv.w;
    }
    lg[u] = a*0.17677669529663687f + gbl[s*SS + tc0 + u];
  }
  float m = lg[0];
  #pragma unroll
  for (int u = 1; u < 16; u++) m = fmaxf(m, lg[u]);
  m = fmaxf(m, __shfl_xor(m, 1));
  m = fmaxf(m, __shfl_xor(m, 2));
  float ssum = 0.f;
  #pragma unroll
  for (int u = 0; u < 16; u++){ lg[u] = expf(lg[u]-m); ssum += lg[u]; }
  ssum += __shfl_xor(ssum, 1);
  ssum += __shfl_xor(ssum, 2);
  float invs = 1.0f/ssum;
  #pragma unroll
  for (int u = 0; u < 16; u++) att[s*SS + tc0+u] = lg[u]*invs;
  __syncthreads();
  float ao[8];
  #pragma unroll
  for (int j = 0; j < 8; j++) ao[j] = 0.f;
  for (int t2 = 0; t2 < SS; t2++){
    float a = att[s*SS + t2];
    float4 v0 = *((const float4*)&vh[t2][d0]);
    float4 v1 = *((const float4*)&vh[t2][d0+4]);
    ao[0]+=a*v0.x; ao[1]+=a*v0.y; ao[2]+=a*v0.z; ao[3]+=a*v0.w;
    ao[4]+=a*v1.x; ao[5]+=a*v1.y; ao[6]+=a*v1.z; ao[7]+=a*v1.w;
  }
  float* sop = so + ((size_t)b*SS + s)*WW + hh*HD + d0;
  *((float4*)sop)     = make_float4(ao[0],ao[1],ao[2],ao[3]);
  *((float4*)(sop+4)) = make_float4(ao[4],ao[5],ao[6],ao[7]);
}

// ------------------------------------------------- output projection
__global__ __launch_bounds__(256) void k_oproj(
    const float* __restrict__ so, const float* __restrict__ ow,
    const float* __restrict__ ob, float* __restrict__ so_out)
{
  __shared__ float st[16][WW];
  const int t = threadIdx.x;
  const int b = blockIdx.y;
  const int s0 = blockIdx.x * 16;
  {
    const float4* sp = (const float4*)(so + ((size_t)b*SS + s0)*WW);
    float4* st4 = (float4*)st;
    #pragma unroll
    for (int i = 0; i < 4; i++) st4[t + 256*i] = sp[t + 256*i];
  }
  __syncthreads();
  float acc[16];
  float bias = ob[t];
  #pragma unroll
  for (int i = 0; i < 16; i++) acc[i] = bias;
  for (int k4 = 0; k4 < 64; k4++){
    float w0 = ow[(size_t)(k4*4+0)*WW + t];
    float w1 = ow[(size_t)(k4*4+1)*WW + t];
    float w2 = ow[(size_t)(k4*4+2)*WW + t];
    float w3 = ow[(size_t)(k4*4+3)*WW + t];
    #pragma unroll
    for (int i = 0; i < 16; i++){
      float4 sv = *((const float4*)&st[i][k4*4]);
      acc[i] += sv.x*w0 + sv.y*w1 + sv.z*w2 + sv.w*w3;
    }
  }
  #pragma unroll
  for (int i = 0; i < 16; i++)
    so_out[((size_t)b*SS + s0 + i)*WW + t] = acc[i];
}

// ------------------------------------------------- W1 prep: [256 k][1024 j] f32
// -> w1tb [1024 j][256 k] bf16, k-groups (16B=8 elts) XOR'd by (j&7).
__global__ __launch_bounds__(256) void k_tr1(
    const float* __restrict__ in, short* __restrict__ out)
{
  __shared__ float tile[32][33];
  const int tx = threadIdx.x & 31;
  const int ty = threadIdx.x >> 5;   // 0..7
  const size_t moff = (size_t)blockIdx.z * WW * NF;
  const int x = blockIdx.x*32 + tx;  // j
  const int y0 = blockIdx.y*32;      // k base
  #pragma unroll
  for (int i = 0; i < 4; i++){
    int r = y0 + ty + i*8;           // k
    tile[ty + i*8][tx] = in[moff + (size_t)r*NF + x];
  }
  __syncthreads();
  const int k = y0 + tx;
  #pragma unroll
  for (int i = 0; i < 4; i++){
    int j = blockIdx.x*32 + ty + i*8;
    int off = j*WW + ((((k>>3) ^ (j&7)))<<3) + (k&7);
    out[moff + off] = f2bf(tile[tx][ty + i*8]);
  }
}

// ------------------------------------------------- W2 prep: [1024 j][256 c] f32
// -> w2tb chunk-major [32 ch][256 c][32 jl] bf16, j-groups XOR'd by (c&3).
__global__ __launch_bounds__(256) void k_tr2(
    const float* __restrict__ in, short* __restrict__ out)
{
  __shared__ float tile[32][33];
  const int tx = threadIdx.x & 31;
  const int ty = threadIdx.x >> 5;
  const size_t moff = (size_t)blockIdx.z * NF * WW;
  const int x = blockIdx.x*32 + tx;  // c
  const int y0 = blockIdx.y*32;      // j base (chunk-aligned)
  #pragma unroll
  for (int i = 0; i < 4; i++){
    int r = y0 + ty + i*8;           // j
    tile[ty + i*8][tx] = in[moff + (size_t)r*WW + x];
  }
  __syncthreads();
  const int ch = y0 >> 5;            // chunk id
  const int jl = tx;                 // j within chunk
  #pragma unroll
  for (int i = 0; i < 4; i++){
    int c = blockIdx.x*32 + ty + i*8;
    int off = ch*8192 + c*32 + ((((jl>>3) ^ (c&3)))<<3) + (jl&7);
    out[moff + off] = f2bf(tile[tx][ty + i*8]);
  }
}

// ------------------------------------------------- fused hupd + LN2 + FFN
// (round-9 proven version)
#define FTM 64
#define CH 32
__global__ __launch_bounds__(256, 4) void k_ffn8(
    float* __restrict__ h, const float* __restrict__ wts,
    const float* __restrict__ so_out,
    const float* __restrict__ lnw, const float* __restrict__ lnb,
    const short* __restrict__ w1t, const float* __restrict__ b1,
    const short* __restrict__ w2t, const float* __restrict__ b2)
{
  __shared__ __align__(16) char wbig[32768];       // w1s+w2s  OR  sob[64][128]
  __align__(16) __shared__ short gbuf[4][16*40];   // 5 KB, per-wave
  short* w1s = (short*)wbig;
  short* w2s = (short*)(wbig + 16384);
  float* sob = (float*)wbig;
  const int t = threadIdx.x;
  const int w = t >> 6, l = t & 63;
  const int lm = l & 15, g = l >> 4;
  const int b = blockIdx.y;
  const int ltok0 = blockIdx.x * FTM;
  const bool valid = (ltok0 + w*16) < NN;          // wave-uniform
  const int lA = valid ? (ltok0 + w*16 + lm) : lm; // clamped local token
  const size_t tokA = (size_t)b*NN + lA;
  float* hrow = h + tokA*WW;
  const float* wrow = wts + tokA*SS;

  // ---- fused h-update + LN stats, two column halves ----
  float sum = 0.f, sq = 0.f;
  #pragma unroll
  for (int half = 0; half < 2; half++){
    __syncthreads();     // prior use of wbig (sob reads of previous half) done
    #pragma unroll
    for (int it = 0; it < 8; it++){
      int idx = it*256 + t;                 // 0..2047
      int s = idx >> 5, c4 = (idx & 31) << 2;
      GLOAD16(so_out + ((size_t)b*SS + s)*WW + half*128 + c4,
              ((float*)sob) + (size_t)idx*4);
    }
    __syncthreads();     // staged (vmcnt drained by barrier)
    float4 hv[8], upd[8];
    #pragma unroll
    for (int u = 0; u < 8; u++){
      hv[u] = *(const float4*)(hrow + (half*4 + (u>>1))*32 + g*8 + (u&1)*4);
      upd[u] = make_float4(0.f,0.f,0.f,0.f);
    }
    #pragma unroll 2
    for (int s4 = 0; s4 < 16; s4++){
      float4 wv4 = *(const float4*)(wrow + s4*4);
      #pragma unroll
      for (int k = 0; k < 4; k++){
        float wv = (k==0)?wv4.x:(k==1)?wv4.y:(k==2)?wv4.z:wv4.w;
        const float* sor = sob + (s4*4+k)*128 + g*8;
        #pragma unroll
        for (int u = 0; u < 8; u++){
          float4 so4 = *(const float4*)(sor + (u>>1)*32 + (u&1)*4);
          upd[u].x += wv*so4.x; upd[u].y += wv*so4.y;
          upd[u].z += wv*so4.z; upd[u].w += wv*so4.w;
        }
      }
    }
    #pragma unroll
    for (int u = 0; u < 8; u++){
      float4 nv;
      nv.x = hv[u].x + upd[u].x; nv.y = hv[u].y + upd[u].y;
      nv.z = hv[u].z + upd[u].z; nv.w = hv[u].w + upd[u].w;
      sum += nv.x+nv.y+nv.z+nv.w;
      sq  += nv.x*nv.x+nv.y*nv.y+nv.z*nv.z+nv.w*nv.w;
      if (valid)
        *(float4*)(hrow + (half*4 + (u>>1))*32 + g*8 + (u&1)*4) = nv;
    }
  }
  sum += __shfl_xor(sum, 16); sum += __shfl_xor(sum, 32);
  sq  += __shfl_xor(sq, 16);  sq  += __shfl_xor(sq, 32);
  float mu = sum*(1.0f/WW);
  float var = sq*(1.0f/WW) - mu*mu;
  float rs = rsqrtf(var + 1e-5f);
  // ---- build bf16 LN2 fragments (re-read h_new, L2-hot) ----
  short8v hn[8];
  #pragma unroll
  for (int f = 0; f < 8; f++){
    float4 a  = *(const float4*)(hrow + f*32 + g*8);
    float4 bq = *(const float4*)(hrow + f*32 + g*8 + 4);
    float4 w0 = *(const float4*)(lnw + f*32 + g*8);
    float4 w1 = *(const float4*)(lnw + f*32 + g*8 + 4);
    float4 b0 = *(const float4*)(lnb + f*32 + g*8);
    float4 b1v = *(const float4*)(lnb + f*32 + g*8 + 4);
    short8v fr;
    fr[0] = f2bf((a.x -mu)*rs*w0.x + b0.x);
    fr[1] = f2bf((a.y -mu)*rs*w0.y + b0.y);
    fr[2] = f2bf((a.z -mu)*rs*w0.z + b0.z);
    fr[3] = f2bf((a.w -mu)*rs*w0.w + b0.w);
    fr[4] = f2bf((bq.x-mu)*rs*w1.x + b1v.x);
    fr[5] = f2bf((bq.y-mu)*rs*w1.y + b1v.y);
    fr[6] = f2bf((bq.z-mu)*rs*w1.z + b1v.z);
    fr[7] = f2bf((bq.w-mu)*rs*w1.w + b1v.w);
    hn[f] = fr;
  }
  f32x4 acc2[16];
  #pragma unroll
  for (int ct = 0; ct < 16; ct++)
    acc2[ct] = (f32x4){0.f,0.f,0.f,0.f};
  __syncthreads();   // sob reads done; wbig free for weight staging

  for (int ch = 0; ch < NF/CH; ch++){
    const int j0 = ch*CH;
    const short* w1c = w1t + (size_t)j0*256;
    const short* w2c = w2t + (size_t)ch*8192;
    #pragma unroll
    for (int it = 0; it < 4; it++){
      int p = w*4 + it;
      GLOAD16(w1c + p*512 + l*8, w1s + p*512);
      GLOAD16(w2c + p*512 + l*8, w2s + p*512);
    }
    __syncthreads();
    #pragma unroll
    for (int jt = 0; jt < 2; jt++){
      f32x4 d0 = (f32x4){0.f,0.f,0.f,0.f};
      const int rl = jt*16 + lm;
      #pragma unroll
      for (int ks = 0; ks < 8; ks++){
        short8v af = *(const short8v*)(w1s + rl*256 + ((((ks<<2)|g) ^ (rl&7))<<3));
        d0 = __builtin_amdgcn_mfma_f32_16x16x32_bf16(af, hn[ks], d0, 0, 0, 0);
      }
      float4 bb = *(const float4*)(b1 + j0 + jt*16 + g*4);
      float x0 = gelu_f(d0[0] + bb.x), x1 = gelu_f(d0[1] + bb.y);
      float x2 = gelu_f(d0[2] + bb.z), x3 = gelu_f(d0[3] + bb.w);
      unsigned u0 = (unsigned)(unsigned short)f2bf(x0) | ((unsigned)(unsigned short)f2bf(x1) << 16);
      unsigned u1 = (unsigned)(unsigned short)f2bf(x2) | ((unsigned)(unsigned short)f2bf(x3) << 16);
      *(uint2*)(&gbuf[w][lm*40 + jt*16 + g*4]) = make_uint2(u0, u1);
    }
    // same-wave produce->consume on gbuf[w]: DS pipe in-order, no barrier
    short8v gA0 = *(const short8v*)(&gbuf[w][lm*40 + g*8]);
    #pragma unroll
    for (int ct = 0; ct < 16; ct++){
      const int row = ct*16 + lm;
      short8v a0 = *(const short8v*)(w2s + row*32 + (((g ^ (row&3)))<<3));
      acc2[ct] = __builtin_amdgcn_mfma_f32_16x16x32_bf16(a0, gA0, acc2[ct], 0, 0, 0);
    }
    __syncthreads();
  }
  // ---- epilogue: per-tile LDS transpose, h_final = h_new + ffn + b2 ----
  if (valid){
    float* tb = (float*)&gbuf[w][0];       // [16][20] f32 scratch (per-wave)
    const int tok_l = l >> 2, cq = (l & 3)*4;
    const size_t trow = (size_t)b*NN + ltok0 + w*16;
    #pragma unroll
    for (int ct = 0; ct < 16; ct++){
      float4 sv;
      sv.x = acc2[ct][0]; sv.y = acc2[ct][1];
      sv.z = acc2[ct][2]; sv.w = acc2[ct][3];
      *(float4*)(&tb[lm*20 + g*4]) = sv;
      float4 tv = *(const float4*)(&tb[tok_l*20 + cq]);
      float4 bb = *(const float4*)(b2 + ct*16 + cq);
      float* hp = h + (trow + tok_l)*WW + ct*16 + cq;
      float4 ho = *(const float4*)hp;
      ho.x += tv.x + bb.x; ho.y += tv.y + bb.y;
      ho.z += tv.z + bb.z; ho.w += tv.w + bb.w;
      *(float4*)hp = ho;
    }
  }
}

// ------------------------------------------------- final projection
__global__ __launch_bounds__(256) void k_out(
    const float* __restrict__ h, const float* __restrict__ ow,
    const float* __restrict__ ob, float* __restrict__ out)
{
  size_t n = (size_t)blockIdx.x*256 + threadIdx.x;
  if (n >= (size_t)BB*NN) return;
  float a0=ob[0], a1=ob[1], a2=ob[2], a3=ob[3];
  const float4* hp = (const float4*)(h + n*WW);
  const float4* ow4 = (const float4*)ow;
  for (int c4 = 0; c4 < 64; c4++){
    float4 hv = hp[c4];
    float4 w0 = ow4[c4*4+0], w1 = ow4[c4*4+1], w2 = ow4[c4*4+2], w3 = ow4[c4*4+3];
    a0 += hv.x*w0.x + hv.y*w1.x + hv.z*w2.x + hv.w*w3.x;
    a1 += hv.x*w0.y + hv.y*w1.y + hv.z*w2.y + hv.w*w3.y;
    a2 += hv.x*w0.z + hv.y*w1.z + hv.z*w2.z + hv.w*w3.z;
    a3 += hv.x*w0.w + hv.y*w1.w + hv.z*w2.w + hv.w*w3.w;
  }
  *((float4*)(out + n*4)) = make_float4(a0,a1,a2,a3);
}

// =================================================================
extern "C" void kernel_launch(void* const* d_in, const int* in_sizes, int n_in,
                              void* d_out, int out_size, void* d_ws, size_t ws_size,
                              hipStream_t stream) {
  const float* fields    = (const float*)d_in[0];
  const float* coords    = (const float*)d_in[1];
  const float* t_norm    = (const float*)d_in[2];
  const float* adj_vals  = (const float*)d_in[3];
  const float* freq      = (const float*)d_in[4];
  const float* omega     = (const float*)d_in[5];
  const float* in_w      = (const float*)d_in[6];
  const float* in_b      = (const float*)d_in[7];
  const float* ln1_w     = (const float*)d_in[8];
  const float* ln1_b     = (const float*)d_in[9];
  const float* ln2_w     = (const float*)d_in[10];
  const float* ln2_b     = (const float*)d_in[11];
  const float* slice_w   = (const float*)d_in[12];
  const float* slice_b   = (const float*)d_in[13];
  const float* q_w       = (const float*)d_in[14];
  const float* q_b       = (const float*)d_in[15];
  const float* k_w       = (const float*)d_in[16];
  const float* k_b       = (const float*)d_in[17];
  const float* v_w       = (const float*)d_in[18];
  const float* v_b       = (const float*)d_in[19];
  const float* o_w       = (const float*)d_in[20];
  const float* o_b       = (const float*)d_in[21];
  const float* beta_raw  = (const float*)d_in[22];
  const float* ffn1_w    = (const float*)d_in[23];
  const float* ffn1_b    = (const float*)d_in[24];
  const float* ffn2_w    = (const float*)d_in[25];
  const float* ffn2_b    = (const float*)d_in[26];
  const float* out_w     = (const float*)d_in[27];
  const float* out_b     = (const float*)d_in[28];
  const int*   adj       = (const int*)d_in[29];
  float* out = (float*)d_out;

  float* ws = (float*)d_ws;
  size_t off = 0;
  float* h        = ws + off; off += (size_t)BB*NN*WW;
  float* wts      = ws + off; off += (size_t)BB*NN*SS;
  float* mu_rstd  = ws + off; off += (size_t)BB*NN*2;
  float* sacc     = ws + off; off += (size_t)BB*SS*WW;   // zeroed per layer
  float* wsumb    = ws + off; off += (size_t)BB*SS;      // zeroed per layer
  float* gb       = ws + off; off += (size_t)BB*SS*SS;   // zeroed per layer
  float* so       = ws + off; off += (size_t)BB*SS*WW;
  float* so_out   = ws + off; off += (size_t)BB*SS*WW;
  short* w1tb     = (short*)(ws + off); off += (size_t)NL*WW*NF/2;  // bf16 W1^T swz
  short* w2tb     = (short*)(ws + off); off += (size_t)NL*WW*NF/2;  // bf16 W2 chunk-major swz
  short* wtsb     = (short*)(ws + off); off += (size_t)BB*NN*SS/2;  // bf16 wts

  hipLaunchKernelGGL(k_tr1, dim3(NF/32, WW/32, NL), dim3(256), 0, stream,
      ffn1_w, w1tb);
  hipLaunchKernelGGL(k_tr2, dim3(WW/32, NF/32, NL), dim3(256), 0, stream,
      ffn2_w, w2tb);

  hipLaunchKernelGGL(k_embed, dim3(BB*NN/16), dim3(256), 0, stream,
      fields, coords, t_norm, freq, omega, in_w, in_b, h);

  for (int l = 0; l < NL; l++){
    hipMemsetAsync(sacc, 0,
        (size_t)(BB*SS*WW + BB*SS + BB*SS*SS)*sizeof(float), stream);
    hipLaunchKernelGGL(k_lnw, dim3(BB*NN/16), dim3(256), 0, stream,
        h, ln1_w + l*WW, ln1_b + l*WW,
        slice_w + (size_t)l*WW*SS, slice_b + l*SS, wts, wtsb, mu_rstd);
    hipLaunchKernelGGL(k_slices, dim3(157, BB), dim3(256), 0, stream,
        h, wts, mu_rstd, ln1_w + l*WW, ln1_b + l*WW, sacc, wsumb);
    hipLaunchKernelGGL(k_gb2, dim3(GB_BLKS), dim3(256), 0, stream,
        wtsb, adj, adj_vals, gb);
    hipLaunchKernelGGL(k_attn, dim3(NH, BB), dim3(256), 0, stream,
        sacc, wsumb, gb, beta_raw, l,
        q_w + (size_t)l*WW*WW, q_b + l*WW,
        k_w + (size_t)l*WW*WW, k_b + l*WW,
        v_w + (size_t)l*WW*WW, v_b + l*WW,
        so);
    hipLaunchKernelGGL(k_oproj, dim3(4, BB), dim3(256), 0, stream,
        so, o_w + (size_t)l*WW*WW, o_b + l*WW, so_out);
    hipLaunchKernelGGL(k_ffn8, dim3((NN + FTM - 1)/FTM, BB), dim3(256), 0, stream,
        h, wts, so_out, ln2_w + l*WW, ln2_b + l*WW,
        w1tb + (size_t)l*WW*NF, ffn1_b + l*NF,
        w2tb + (size_t)l*WW*NF, ffn2_b + l*WW);
  }

  hipLaunchKernelGGL(k_out, dim3((BB*NN + 255)/256), dim3(256), 0, stream,
      h, out_w, out_b, out);
}

// Round 16
// 3091.430 us; speedup vs baseline: 1.0952x; 1.0952x over previous
//
#include <hip/hip_runtime.h>
#include <math.h>

#define BB 4
#define NN 20000
#define NE 320000
#define WW 256
#define SS 64
#define NH 8
#define HD 32
#define NF 1024
#define NL 4
#define GEPS 1e-6f

typedef __attribute__((ext_vector_type(8))) short short8v;
typedef __attribute__((ext_vector_type(4))) float f32x4;

static __device__ __forceinline__ short f2bf(float x){
  union { float f; unsigned u; } v; v.f = x;
  unsigned r = v.u + 0x7fffu + ((v.u >> 16) & 1u);
  return (short)(r >> 16);
}
static __device__ __forceinline__ float bfu_lo(unsigned u){
  union { unsigned u; float f; } v; v.u = u << 16; return v.f;
}
static __device__ __forceinline__ float bfu_hi(unsigned u){
  union { unsigned u; float f; } v; v.u = u & 0xffff0000u; return v.f;
}
static __device__ __forceinline__ float gelu_f(float x){
  return 0.5f*x*(1.0f + erff(x*0.70710678118654752f));
}

#define GLOAD16(gsrc, ldst) \
  __builtin_amdgcn_global_load_lds( \
      (const __attribute__((address_space(1))) void*)(gsrc), \
      (__attribute__((address_space(3))) void*)(ldst), 16, 0, 0)

// ---------------------------------------------------------------- embed
__global__ __launch_bounds__(256) void k_embed(
    const float* __restrict__ fields, const float* __restrict__ coords,
    const float* __restrict__ t_norm, const float* __restrict__ freq,
    const float* __restrict__ omega, const float* __restrict__ in_w,
    const float* __restrict__ in_b, float* __restrict__ h)
{
  __shared__ float inv[16][28];
  __shared__ float temb[8];
  const int t = threadIdx.x;
  const size_t tok0 = (size_t)blockIdx.x * 16;
  const int b = (int)(tok0 / NN);
  if (t < 8) {
    int f = t & 3;
    float ang = t_norm[b] * 1000.0f * omega[f];
    temb[t] = (t < 4) ? sinf(ang) : cosf(ang);
  }
  if (t < 128) {
    int tok = t >> 3, f = t & 7;
    size_t n = tok0 + tok;
    float c0 = coords[n*2+0], c1 = coords[n*2+1];
    float sp = 6.283185307179586f * (c0*freq[f] + c1*freq[8+f]);
    inv[tok][4+f]  = sinf(sp);
    inv[tok][12+f] = cosf(sp);
  } else if (t < 192) {
    int idx = t - 128; int tok = idx >> 2, i = idx & 3;
    inv[tok][i] = fields[(tok0+tok)*4 + i];
  }
  __syncthreads();
  if (t < 128) {
    int tok = t >> 3, f = t & 7;
    inv[tok][20+f] = temb[f];
  }
  __syncthreads();
  float acc[16];
  float bias = in_b[t];
  #pragma unroll
  for (int i = 0; i < 16; i++) acc[i] = bias;
  #pragma unroll 4
  for (int k = 0; k < 28; k++) {
    float w = in_w[k*WW + t];
    #pragma unroll
    for (int i = 0; i < 16; i++) acc[i] += inv[i][k]*w;
  }
  #pragma unroll
  for (int i = 0; i < 16; i++) h[(tok0+i)*WW + t] = acc[i];
}

// ------------------------------------------------- LN1 + slice weights
__global__ __launch_bounds__(256) void k_lnw(
    const float* __restrict__ h, const float* __restrict__ lnw,
    const float* __restrict__ lnb, const float* __restrict__ sw,
    const float* __restrict__ sb, float* __restrict__ wts,
    short* __restrict__ wtsb, float* __restrict__ mu_rstd)
{
  __shared__ float hn[16][WW];
  __shared__ float ps[16][16], pq[16][16];
  __shared__ float mus[16], rss[16];
  const int t = threadIdx.x;
  const size_t tok0 = (size_t)blockIdx.x * 16;
  const int tok = t >> 4, seg = t & 15;
  {
    const float4* hp = (const float4*)(h + (tok0+tok)*WW + seg*16);
    float sum = 0.f, sq = 0.f;
    #pragma unroll
    for (int i = 0; i < 4; i++){
      float4 v = hp[i];
      sum += v.x+v.y+v.z+v.w;
      sq  += v.x*v.x+v.y*v.y+v.z*v.z+v.w*v.w;
      *((float4*)&hn[tok][seg*16 + i*4]) = v;
    }
    ps[tok][seg] = sum; pq[tok][seg] = sq;
  }
  __syncthreads();
  if (t < 16){
    float s0=0.f, q0=0.f;
    #pragma unroll
    for (int i = 0; i < 16; i++){ s0 += ps[t][i]; q0 += pq[t][i]; }
    float mu = s0*(1.0f/WW);
    float var = q0*(1.0f/WW) - mu*mu;
    float rs = rsqrtf(var + 1e-5f);
    mus[t] = mu; rss[t] = rs;
    mu_rstd[(tok0 + t)*2]     = mu;
    mu_rstd[(tok0 + t)*2 + 1] = rs;
  }
  __syncthreads();
  {
    float mu = mus[tok], rs = rss[tok];
    #pragma unroll
    for (int i = 0; i < 16; i++){
      int c = seg*16 + i;
      hn[tok][c] = (hn[tok][c]-mu)*rs*lnw[c] + lnb[c];
    }
  }
  __syncthreads();
  const int s = t & 63, tg = t >> 6;
  float acc[4];
  float bs = sb[s];
  #pragma unroll
  for (int i = 0; i < 4; i++) acc[i] = bs;
  for (int c4 = 0; c4 < 64; c4++){
    float w0 = sw[(c4*4+0)*SS + s];
    float w1 = sw[(c4*4+1)*SS + s];
    float w2 = sw[(c4*4+2)*SS + s];
    float w3 = sw[(c4*4+3)*SS + s];
    #pragma unroll
    for (int i = 0; i < 4; i++){
      float4 hv = *((const float4*)&hn[tg*4+i][c4*4]);
      acc[i] += hv.x*w0 + hv.y*w1 + hv.z*w2 + hv.w*w3;
    }
  }
  #pragma unroll
  for (int i = 0; i < 4; i++){
    float m = acc[i];
    #pragma unroll
    for (int off = 32; off > 0; off >>= 1) m = fmaxf(m, __shfl_xor(m, off));
    float e = expf(acc[i] - m);
    float ssum = e;
    #pragma unroll
    for (int off = 32; off > 0; off >>= 1) ssum += __shfl_xor(ssum, off);
    float wv = e/ssum;
    wts[(tok0 + tg*4 + i)*SS + s] = wv;
    wtsb[(tok0 + tg*4 + i)*SS + s] = f2bf(wv);
  }
}

// ------------------------------------------------- slices partial sums
__global__ __launch_bounds__(256) void k_slices(
    const float* __restrict__ h, const float* __restrict__ wts,
    const float* __restrict__ mu_rstd, const float* __restrict__ lnw,
    const float* __restrict__ lnb, float* __restrict__ sacc,
    float* __restrict__ wsum)
{
  __shared__ float wstage[16][SS];
  const int t = threadIdx.x;
  const int b = blockIdx.y;
  const int n0 = blockIdx.x * 128;
  const float lw = lnw[t], lb = lnb[t];
  float acc[SS];
  #pragma unroll
  for (int s = 0; s < SS; s++) acc[s] = 0.f;
  float wsl = 0.f;
  for (int it = 0; it < 8; it++){
    int nb = n0 + it*16;
    {
      int tk = t >> 4, s4 = (t & 15)*4;
      int n = nb + tk;
      float4 v = make_float4(0.f,0.f,0.f,0.f);
      if (n < NN) v = *((const float4*)(wts + ((size_t)b*NN + n)*SS + s4));
      *((float4*)&wstage[tk][s4]) = v;
    }
    __syncthreads();
    #pragma unroll 4
    for (int tk = 0; tk < 16; tk++){
      int n = nb + tk;
      if (n < NN){
        size_t g = (size_t)b*NN + n;
        float mu = mu_rstd[g*2], rsd = mu_rstd[g*2+1];
        float hv = h[g*WW + t];
        float hnv = (hv-mu)*rsd*lw + lb;
        #pragma unroll
        for (int s4 = 0; s4 < 16; s4++){
          float4 wv = *((const float4*)&wstage[tk][s4*4]);
          acc[s4*4+0] += wv.x*hnv;
          acc[s4*4+1] += wv.y*hnv;
          acc[s4*4+2] += wv.z*hnv;
          acc[s4*4+3] += wv.w*hnv;
        }
      }
    }
    if (t < SS){
      #pragma unroll
      for (int tk = 0; tk < 16; tk++) wsl += wstage[tk][t];
    }
    __syncthreads();
  }
  #pragma unroll
  for (int s = 0; s < SS; s++)
    atomicAdd(&sacc[((size_t)b*SS + s)*WW + t], acc[s]);
  if (t < SS) atomicAdd(&wsum[b*SS + t], wsl);
}

// ------------------------------------------------- gb edge accumulation (v2)
#define GB_BLKS 1000
#define GB_PB   250
#define GB_EDG  (NE/GB_PB)    // 1280
__global__ __launch_bounds__(256) void k_gb2(
    const short* __restrict__ wtsb, const int* __restrict__ adj,
    const float* __restrict__ vals, float* __restrict__ gb)
{
  __shared__ float gbw[SS*SS];
  const int t = threadIdx.x;
  const int bid = blockIdx.x;
  const int xcd = bid & 7;
  const int b = xcd >> 1;                        // batch -> XCD pair
  const int grp = (bid >> 3)*2 + (xcd & 1);      // 0..249 within batch
  const int e0 = grp * GB_EDG;
  const int w = t >> 6, l = t & 63;
  const int sg = l >> 3, tg = l & 7;
  #pragma unroll
  for (int i = 0; i < 16; i++) gbw[t + 256*i] = 0.f;
  __syncthreads();
  float acc[8][8];
  #pragma unroll
  for (int i = 0; i < 8; i++)
    #pragma unroll
    for (int u = 0; u < 8; u++) acc[i][u] = 0.f;
  const short* wb = wtsb + (size_t)b*NN*SS;
  for (int e = e0 + w; e < e0 + GB_EDG; e += 8){
    int row0 = adj[e],     col0 = adj[NE + e];
    int row1 = adj[e + 4], col1 = adj[NE + e + 4];
    float v0 = vals[e], v1 = vals[e + 4];
    uint4 ru0 = *(const uint4*)(wb + (size_t)row0*SS + sg*8);
    uint4 cu0 = *(const uint4*)(wb + (size_t)col0*SS + tg*8);
    uint4 ru1 = *(const uint4*)(wb + (size_t)row1*SS + sg*8);
    uint4 cu1 = *(const uint4*)(wb + (size_t)col1*SS + tg*8);
    float rr[8], cc[8];
    rr[0]=bfu_lo(ru0.x)*v0; rr[1]=bfu_hi(ru0.x)*v0;
    rr[2]=bfu_lo(ru0.y)*v0; rr[3]=bfu_hi(ru0.y)*v0;
    rr[4]=bfu_lo(ru0.z)*v0; rr[5]=bfu_hi(ru0.z)*v0;
    rr[6]=bfu_lo(ru0.w)*v0; rr[7]=bfu_hi(ru0.w)*v0;
    cc[0]=bfu_lo(cu0.x); cc[1]=bfu_hi(cu0.x);
    cc[2]=bfu_lo(cu0.y); cc[3]=bfu_hi(cu0.y);
    cc[4]=bfu_lo(cu0.z); cc[5]=bfu_hi(cu0.z);
    cc[6]=bfu_lo(cu0.w); cc[7]=bfu_hi(cu0.w);
    #pragma unroll
    for (int i = 0; i < 8; i++)
      #pragma unroll
      for (int u = 0; u < 8; u++) acc[i][u] += rr[i]*cc[u];
    rr[0]=bfu_lo(ru1.x)*v1; rr[1]=bfu_hi(ru1.x)*v1;
    rr[2]=bfu_lo(ru1.y)*v1; rr[3]=bfu_hi(ru1.y)*v1;
    rr[4]=bfu_lo(ru1.z)*v1; rr[5]=bfu_hi(ru1.z)*v1;
    rr[6]=bfu_lo(ru1.w)*v1; rr[7]=bfu_hi(ru1.w)*v1;
    cc[0]=bfu_lo(cu1.x); cc[1]=bfu_hi(cu1.x);
    cc[2]=bfu_lo(cu1.y); cc[3]=bfu_hi(cu1.y);
    cc[4]=bfu_lo(cu1.z); cc[5]=bfu_hi(cu1.z);
    cc[6]=bfu_lo(cu1.w); cc[7]=bfu_hi(cu1.w);
    #pragma unroll
    for (int i = 0; i < 8; i++)
      #pragma unroll
      for (int u = 0; u < 8; u++) acc[i][u] += rr[i]*cc[u];
  }
  #pragma unroll
  for (int i = 0; i < 8; i++)
    #pragma unroll
    for (int u = 0; u < 8; u++)
      atomicAdd(&gbw[(sg*8+i)*SS + tg*8 + u], acc[i][u]);
  __syncthreads();
  #pragma unroll
  for (int i = 0; i < 16; i++){
    int idx = t + 256*i;
    atomicAdd(&gb[(size_t)b*SS*SS + idx], gbw[idx]);
  }
}

// ------------------- attention per (head,b), with fused slices_fin + gbfin
__global__ __launch_bounds__(256) void k_attn(
    const float* __restrict__ sacc, const float* __restrict__ wsum,
    const float* __restrict__ gbin, const float* __restrict__ beta_raw,
    int layer,
    const float* __restrict__ qw, const float* __restrict__ qb,
    const float* __restrict__ kw, const float* __restrict__ kb,
    const float* __restrict__ vw, const float* __restrict__ vb,
    float* __restrict__ so)
{
  __shared__ float sl[SS][WW];          // 64 KB
  __shared__ float qh[SS][HD], kh[SS][HD], vh[SS][HD];   // 24 KB
  __shared__ float att[SS*SS];          // 16 KB (first used as gb scratch)
  __shared__ float gbl[SS*SS];          // 16 KB
  __shared__ float rws[SS], rs2[SS];
  const int t = threadIdx.x;
  const int hh = blockIdx.x, b = blockIdx.y;
  // phase A: load raw gb into att-scratch; slice normalizers
  #pragma unroll
  for (int i = 0; i < 16; i++)
    att[t + 256*i] = gbin[(size_t)b*SS*SS + t + 256*i];
  if (t < SS) rws[t] = 1.0f / fmaxf(wsum[b*SS + t], GEPS);
  __syncthreads();
  // phase B: symmetrize into gbl; load sl = sacc * rws[s]  (float4: 4096 x 16B)
  #pragma unroll
  for (int i = 0; i < 16; i++){
    int idx = t + 256*i; int r = idx >> 6, c = idx & 63;
    gbl[idx] = 0.5f*(att[idx] + att[c*SS + r]);
  }
  {
    const float4* sp4 = (const float4*)(sacc + (size_t)b*SS*WW);
    float4* sl4 = (float4*)&sl[0][0];
    #pragma unroll
    for (int i = 0; i < 16; i++){
      int idx = t + 256*i;            // 0..4095 float4s; 64 per row
      int s = idx >> 6;
      float r = rws[s];
      float4 v = sp4[idx];
      v.x *= r; v.y *= r; v.z *= r; v.w *= r;
      sl4[idx] = v;
    }
  }
  __syncthreads();
  // phase C: gb row sums
  if (t < SS){
    float sum = 0.f;
    for (int c = 0; c < SS; c++) sum += gbl[t*SS + c];
    rs2[t] = 1.0f / fmaxf(sum, GEPS);
  }
  __syncthreads();
  // phase D: finalize gbl = beta*log(...) in place
  {
    float beta = log1pf(expf(beta_raw[layer]));
    #pragma unroll
    for (int i = 0; i < 16; i++){
      int idx = t + 256*i; int r = idx >> 6;
      gbl[idx] = beta * logf(fmaxf(gbl[idx]*rs2[r], GEPS));
    }
  }
  // ---- QKV projection (reads sl); gbl writes become visible at the
  //      __syncthreads below, before any gbl read ----
  const int s = t >> 2, dq = t & 3, d0 = dq*8;
  float aq[8], ak[8], av[8];
  #pragma unroll
  for (int j = 0; j < 8; j++){
    aq[j] = qb[hh*HD + d0 + j];
    ak[j] = kb[hh*HD + d0 + j];
    av[j] = vb[hh*HD + d0 + j];
  }
  for (int c = 0; c < WW; c++){
    float sv = sl[s][c];
    const float4* q4 = (const float4*)(qw + (size_t)c*WW + hh*HD + d0);
    const float4* k4 = (const float4*)(kw + (size_t)c*WW + hh*HD + d0);
    const float4* v4 = (const float4*)(vw + (size_t)c*WW + hh*HD + d0);
    float4 qa = q4[0], qc = q4[1];
    float4 ka = k4[0], kc = k4[1];
    float4 va = v4[0], vc = v4[1];
    aq[0]+=sv*qa.x; aq[1]+=sv*qa.y; aq[2]+=sv*qa.z; aq[3]+=sv*qa.w;
    aq[4]+=sv*qc.x; aq[5]+=sv*qc.y; aq[6]+=sv*qc.z; aq[7]+=sv*qc.w;
    ak[0]+=sv*ka.x; ak[1]+=sv*ka.y; ak[2]+=sv*ka.z; ak[3]+=sv*ka.w;
    ak[4]+=sv*kc.x; ak[5]+=sv*kc.y; ak[6]+=sv*kc.z; ak[7]+=sv*kc.w;
    av[0]+=sv*va.x; av[1]+=sv*va.y; av[2]+=sv*va.z; av[3]+=sv*va.w;
    av[4]+=sv*vc.x; av[5]+=sv*vc.y; av[6]+=sv*vc.z; av[7]+=sv*vc.w;
  }
  *((float4*)&qh[s][d0])   = make_float4(aq[0],aq[1],aq[2],aq[3]);
  *((float4*)&qh[s][d0+4]) = make_float4(aq[4],aq[5],aq[6],aq[7]);
  *((float4*)&kh[s][d0])   = make_float4(ak[0],ak[1],ak[2],ak[3]);
  *((float4*)&kh[s][d0+4]) = make_float4(ak[4],ak[5],ak[6],ak[7]);
  *((float4*)&vh[s][d0])   = make_float4(av[0],av[1],av[2],av[3]);
  *((float4*)&vh[s][d0+4]) = make_float4(av[4],av[5],av[6],av[7]);
  __syncthreads();
  float qreg[HD];
  #pragma unroll
  for (int d4 = 0; d4 < 8; d4++){
    float4 qv = *((const float4*)&qh[s][d4*4]);
    qreg[d4*4+0]=qv.x; qreg[d4*4+1]=qv.y; qreg[d4*4+2]=qv.z; qreg[d4*4+3]=qv.w;
  }
  const int tc0 = dq*16;
  float lg[16];
  #pragma unroll
  for (int u = 0; u < 16; u++){
    float a = 0.f;
    #pragma unroll
    for (int d4 = 0; d4 < 8; d4++){
      float4 kv = *((const float4*)&kh[tc0+u][d4*4]);
      a += qreg[d4*4+0]*kv.x + qreg[d4*4+1]*kv.y + qreg[d4*4+2]*kv.z + qreg[d4*4+3]*kv.w;
    }
    lg[u] = a*0.17677669529663687f + gbl[s*SS + tc0 + u];
  }
  float m = lg[0];
  #pragma unroll
  for (int u = 1; u < 16; u++) m = fmaxf(m, lg[u]);
  m = fmaxf(m, __shfl_xor(m, 1));
  m = fmaxf(m, __shfl_xor(m, 2));
  float ssum = 0.f;
  #pragma unroll
  for (int u = 0; u < 16; u++){ lg[u] = expf(lg[u]-m); ssum += lg[u]; }
  ssum += __shfl_xor(ssum, 1);
  ssum += __shfl_xor(ssum, 2);
  float invs = 1.0f/ssum;
  #pragma unroll
  for (int u = 0; u < 16; u++) att[s*SS + tc0+u] = lg[u]*invs;
  __syncthreads();
  float ao[8];
  #pragma unroll
  for (int j = 0; j < 8; j++) ao[j] = 0.f;
  for (int t2 = 0; t2 < SS; t2++){
    float a = att[s*SS + t2];
    float4 v0 = *((const float4*)&vh[t2][d0]);
    float4 v1 = *((const float4*)&vh[t2][d0+4]);
    ao[0]+=a*v0.x; ao[1]+=a*v0.y; ao[2]+=a*v0.z; ao[3]+=a*v0.w;
    ao[4]+=a*v1.x; ao[5]+=a*v1.y; ao[6]+=a*v1.z; ao[7]+=a*v1.w;
  }
  float* sop = so + ((size_t)b*SS + s)*WW + hh*HD + d0;
  *((float4*)sop)     = make_float4(ao[0],ao[1],ao[2],ao[3]);
  *((float4*)(sop+4)) = make_float4(ao[4],ao[5],ao[6],ao[7]);
}

// ------------------------------------------------- output projection
__global__ __launch_bounds__(256) void k_oproj(
    const float* __restrict__ so, const float* __restrict__ ow,
    const float* __restrict__ ob, float* __restrict__ so_out)
{
  __shared__ float st[16][WW];
  const int t = threadIdx.x;
  const int b = blockIdx.y;
  const int s0 = blockIdx.x * 16;
  {
    const float4* sp = (const float4*)(so + ((size_t)b*SS + s0)*WW);
    float4* st4 = (float4*)st;
    #pragma unroll
    for (int i = 0; i < 4; i++) st4[t + 256*i] = sp[t + 256*i];
  }
  __syncthreads();
  float acc[16];
  float bias = ob[t];
  #pragma unroll
  for (int i = 0; i < 16; i++) acc[i] = bias;
  for (int k4 = 0; k4 < 64; k4++){
    float w0 = ow[(size_t)(k4*4+0)*WW + t];
    float w1 = ow[(size_t)(k4*4+1)*WW + t];
    float w2 = ow[(size_t)(k4*4+2)*WW + t];
    float w3 = ow[(size_t)(k4*4+3)*WW + t];
    #pragma unroll
    for (int i = 0; i < 16; i++){
      float4 sv = *((const float4*)&st[i][k4*4]);
      acc[i] += sv.x*w0 + sv.y*w1 + sv.z*w2 + sv.w*w3;
    }
  }
  #pragma unroll
  for (int i = 0; i < 16; i++)
    so_out[((size_t)b*SS + s0 + i)*WW + t] = acc[i];
}

// ------------------------------------------------- W1 prep: [256 k][1024 j] f32
// -> w1tb [1024 j][256 k] bf16, k-groups (16B=8 elts) XOR'd by (j&7).
__global__ __launch_bounds__(256) void k_tr1(
    const float* __restrict__ in, short* __restrict__ out)
{
  __shared__ float tile[32][33];
  const int tx = threadIdx.x & 31;
  const int ty = threadIdx.x >> 5;   // 0..7
  const size_t moff = (size_t)blockIdx.z * WW * NF;
  const int x = blockIdx.x*32 + tx;  // j
  const int y0 = blockIdx.y*32;      // k base
  #pragma unroll
  for (int i = 0; i < 4; i++){
    int r = y0 + ty + i*8;           // k
    tile[ty + i*8][tx] = in[moff + (size_t)r*NF + x];
  }
  __syncthreads();
  const int k = y0 + tx;
  #pragma unroll
  for (int i = 0; i < 4; i++){
    int j = blockIdx.x*32 + ty + i*8;
    int off = j*WW + ((((k>>3) ^ (j&7)))<<3) + (k&7);
    out[moff + off] = f2bf(tile[tx][ty + i*8]);
  }
}

// ------------------------------------------------- W2 prep: [1024 j][256 c] f32
// -> w2tb chunk-major [32 ch][256 c][32 jl] bf16, j-groups XOR'd by (c&3).
__global__ __launch_bounds__(256) void k_tr2(
    const float* __restrict__ in, short* __restrict__ out)
{
  __shared__ float tile[32][33];
  const int tx = threadIdx.x & 31;
  const int ty = threadIdx.x >> 5;
  const size_t moff = (size_t)blockIdx.z * NF * WW;
  const int x = blockIdx.x*32 + tx;  // c
  const int y0 = blockIdx.y*32;      // j base (chunk-aligned)
  #pragma unroll
  for (int i = 0; i < 4; i++){
    int r = y0 + ty + i*8;           // j
    tile[ty + i*8][tx] = in[moff + (size_t)r*WW + x];
  }
  __syncthreads();
  const int ch = y0 >> 5;            // chunk id
  const int jl = tx;                 // j within chunk
  #pragma unroll
  for (int i = 0; i < 4; i++){
    int c = blockIdx.x*32 + ty + i*8;
    int off = ch*8192 + c*32 + ((((jl>>3) ^ (c&3)))<<3) + (jl&7);
    out[moff + off] = f2bf(tile[tx][ty + i*8]);
  }
}

// ------------------------------------------------- fused hupd + LN2 + FFN
// (round-9 proven version)
#define FTM 64
#define CH 32
__global__ __launch_bounds__(256, 4) void k_ffn8(
    float* __restrict__ h, const float* __restrict__ wts,
    const float* __restrict__ so_out,
    const float* __restrict__ lnw, const float* __restrict__ lnb,
    const short* __restrict__ w1t, const float* __restrict__ b1,
    const short* __restrict__ w2t, const float* __restrict__ b2)
{
  __shared__ __align__(16) char wbig[32768];       // w1s+w2s  OR  sob[64][128]
  __align__(16) __shared__ short gbuf[4][16*40];   // 5 KB, per-wave
  short* w1s = (short*)wbig;
  short* w2s = (short*)(wbig + 16384);
  float* sob = (float*)wbig;
  const int t = threadIdx.x;
  const int w = t >> 6, l = t & 63;
  const int lm = l & 15, g = l >> 4;
  const int b = blockIdx.y;
  const int ltok0 = blockIdx.x * FTM;
  const bool valid = (ltok0 + w*16) < NN;          // wave-uniform
  const int lA = valid ? (ltok0 + w*16 + lm) : lm; // clamped local token
  const size_t tokA = (size_t)b*NN + lA;
  float* hrow = h + tokA*WW;
  const float* wrow = wts + tokA*SS;

  // ---- fused h-update + LN stats, two column halves ----
  float sum = 0.f, sq = 0.f;
  #pragma unroll
  for (int half = 0; half < 2; half++){
    __syncthreads();     // prior use of wbig (sob reads of previous half) done
    #pragma unroll
    for (int it = 0; it < 8; it++){
      int idx = it*256 + t;                 // 0..2047
      int s = idx >> 5, c4 = (idx & 31) << 2;
      GLOAD16(so_out + ((size_t)b*SS + s)*WW + half*128 + c4,
              ((float*)sob) + (size_t)idx*4);
    }
    __syncthreads();     // staged (vmcnt drained by barrier)
    float4 hv[8], upd[8];
    #pragma unroll
    for (int u = 0; u < 8; u++){
      hv[u] = *(const float4*)(hrow + (half*4 + (u>>1))*32 + g*8 + (u&1)*4);
      upd[u] = make_float4(0.f,0.f,0.f,0.f);
    }
    #pragma unroll 2
    for (int s4 = 0; s4 < 16; s4++){
      float4 wv4 = *(const float4*)(wrow + s4*4);
      #pragma unroll
      for (int k = 0; k < 4; k++){
        float wv = (k==0)?wv4.x:(k==1)?wv4.y:(k==2)?wv4.z:wv4.w;
        const float* sor = sob + (s4*4+k)*128 + g*8;
        #pragma unroll
        for (int u = 0; u < 8; u++){
          float4 so4 = *(const float4*)(sor + (u>>1)*32 + (u&1)*4);
          upd[u].x += wv*so4.x; upd[u].y += wv*so4.y;
          upd[u].z += wv*so4.z; upd[u].w += wv*so4.w;
        }
      }
    }
    #pragma unroll
    for (int u = 0; u < 8; u++){
      float4 nv;
      nv.x = hv[u].x + upd[u].x; nv.y = hv[u].y + upd[u].y;
      nv.z = hv[u].z + upd[u].z; nv.w = hv[u].w + upd[u].w;
      sum += nv.x+nv.y+nv.z+nv.w;
      sq  += nv.x*nv.x+nv.y*nv.y+nv.z*nv.z+nv.w*nv.w;
      if (valid)
        *(float4*)(hrow + (half*4 + (u>>1))*32 + g*8 + (u&1)*4) = nv;
    }
  }
  sum += __shfl_xor(sum, 16); sum += __shfl_xor(sum, 32);
  sq  += __shfl_xor(sq, 16);  sq  += __shfl_xor(sq, 32);
  float mu = sum*(1.0f/WW);
  float var = sq*(1.0f/WW) - mu*mu;
  float rs = rsqrtf(var + 1e-5f);
  // ---- build bf16 LN2 fragments (re-read h_new, L2-hot) ----
  short8v hn[8];
  #pragma unroll
  for (int f = 0; f < 8; f++){
    float4 a  = *(const float4*)(hrow + f*32 + g*8);
    float4 bq = *(const float4*)(hrow + f*32 + g*8 + 4);
    float4 w0 = *(const float4*)(lnw + f*32 + g*8);
    float4 w1 = *(const float4*)(lnw + f*32 + g*8 + 4);
    float4 b0 = *(const float4*)(lnb + f*32 + g*8);
    float4 b1v = *(const float4*)(lnb + f*32 + g*8 + 4);
    short8v fr;
    fr[0] = f2bf((a.x -mu)*rs*w0.x + b0.x);
    fr[1] = f2bf((a.y -mu)*rs*w0.y + b0.y);
    fr[2] = f2bf((a.z -mu)*rs*w0.z + b0.z);
    fr[3] = f2bf((a.w -mu)*rs*w0.w + b0.w);
    fr[4] = f2bf((bq.x-mu)*rs*w1.x + b1v.x);
    fr[5] = f2bf((bq.y-mu)*rs*w1.y + b1v.y);
    fr[6] = f2bf((bq.z-mu)*rs*w1.z + b1v.z);
    fr[7] = f2bf((bq.w-mu)*rs*w1.w + b1v.w);
    hn[f] = fr;
  }
  f32x4 acc2[16];
  #pragma unroll
  for (int ct = 0; ct < 16; ct++)
    acc2[ct] = (f32x4){0.f,0.f,0.f,0.f};
  __syncthreads();   // sob reads done; wbig free for weight staging

  for (int ch = 0; ch < NF/CH; ch++){
    const int j0 = ch*CH;
    const short* w1c = w1t + (size_t)j0*256;
    const short* w2c = w2t + (size_t)ch*8192;
    #pragma unroll
    for (int it = 0; it < 4; it++){
      int p = w*4 + it;
      GLOAD16(w1c + p*512 + l*8, w1s + p*512);
      GLOAD16(w2c + p*512 + l*8, w2s + p*512);
    }
    __syncthreads();
    #pragma unroll
    for (int jt = 0; jt < 2; jt++){
      f32x4 d0 = (f32x4){0.f,0.f,0.f,0.f};
      const int rl = jt*16 + lm;
      #pragma unroll
      for (int ks = 0; ks < 8; ks++){
        short8v af = *(const short8v*)(w1s + rl*256 + ((((ks<<2)|g) ^ (rl&7))<<3));
        d0 = __builtin_amdgcn_mfma_f32_16x16x32_bf16(af, hn[ks], d0, 0, 0, 0);
      }
      float4 bb = *(const float4*)(b1 + j0 + jt*16 + g*4);
      float x0 = gelu_f(d0[0] + bb.x), x1 = gelu_f(d0[1] + bb.y);
      float x2 = gelu_f(d0[2] + bb.z), x3 = gelu_f(d0[3] + bb.w);
      unsigned u0 = (unsigned)(unsigned short)f2bf(x0) | ((unsigned)(unsigned short)f2bf(x1) << 16);
      unsigned u1 = (unsigned)(unsigned short)f2bf(x2) | ((unsigned)(unsigned short)f2bf(x3) << 16);
      *(uint2*)(&gbuf[w][lm*40 + jt*16 + g*4]) = make_uint2(u0, u1);
    }
    // same-wave produce->consume on gbuf[w]: DS pipe in-order, no barrier
    short8v gA0 = *(const short8v*)(&gbuf[w][lm*40 + g*8]);
    #pragma unroll
    for (int ct = 0; ct < 16; ct++){
      const int row = ct*16 + lm;
      short8v a0 = *(const short8v*)(w2s + row*32 + (((g ^ (row&3)))<<3));
      acc2[ct] = __builtin_amdgcn_mfma_f32_16x16x32_bf16(a0, gA0, acc2[ct], 0, 0, 0);
    }
    __syncthreads();
  }
  // ---- epilogue: per-tile LDS transpose, h_final = h_new + ffn + b2 ----
  if (valid){
    float* tb = (float*)&gbuf[w][0];       // [16][20] f32 scratch (per-wave)
    const int tok_l = l >> 2, cq = (l & 3)*4;
    const size_t trow = (size_t)b*NN + ltok0 + w*16;
    #pragma unroll
    for (int ct = 0; ct < 16; ct++){
      float4 sv;
      sv.x = acc2[ct][0]; sv.y = acc2[ct][1];
      sv.z = acc2[ct][2]; sv.w = acc2[ct][3];
      *(float4*)(&tb[lm*20 + g*4]) = sv;
      float4 tv = *(const float4*)(&tb[tok_l*20 + cq]);
      float4 bb = *(const float4*)(b2 + ct*16 + cq);
      float* hp = h + (trow + tok_l)*WW + ct*16 + cq;
      float4 ho = *(const float4*)hp;
      ho.x += tv.x + bb.x; ho.y += tv.y + bb.y;
      ho.z += tv.z + bb.z; ho.w += tv.w + bb.w;
      *(float4*)hp = ho;
    }
  }
}

// ------------------------------------------------- final projection
__global__ __launch_bounds__(256) void k_out(
    const float* __restrict__ h, const float* __restrict__ ow,
    const float* __restrict__ ob, float* __restrict__ out)
{
  size_t n = (size_t)blockIdx.x*256 + threadIdx.x;
  if (n >= (size_t)BB*NN) return;
  float a0=ob[0], a1=ob[1], a2=ob[2], a3=ob[3];
  const float4* hp = (const float4*)(h + n*WW);
  const float4* ow4 = (const float4*)ow;
  for (int c4 = 0; c4 < 64; c4++){
    float4 hv = hp[c4];
    float4 w0 = ow4[c4*4+0], w1 = ow4[c4*4+1], w2 = ow4[c4*4+2], w3 = ow4[c4*4+3];
    a0 += hv.x*w0.x + hv.y*w1.x + hv.z*w2.x + hv.w*w3.x;
    a1 += hv.x*w0.y + hv.y*w1.y + hv.z*w2.y + hv.w*w3.y;
    a2 += hv.x*w0.z + hv.y*w1.z + hv.z*w2.z + hv.w*w3.z;
    a3 += hv.x*w0.w + hv.y*w1.w + hv.z*w2.w + hv.w*w3.w;
  }
  *((float4*)(out + n*4)) = make_float4(a0,a1,a2,a3);
}

// =================================================================
extern "C" void kernel_launch(void* const* d_in, const int* in_sizes, int n_in,
                              void* d_out, int out_size, void* d_ws, size_t ws_size,
                              hipStream_t stream) {
  const float* fields    = (const float*)d_in[0];
  const float* coords    = (const float*)d_in[1];
  const float* t_norm    = (const float*)d_in[2];
  const float* adj_vals  = (const float*)d_in[3];
  const float* freq      = (const float*)d_in[4];
  const float* omega     = (const float*)d_in[5];
  const float* in_w      = (const float*)d_in[6];
  const float* in_b      = (const float*)d_in[7];
  const float* ln1_w     = (const float*)d_in[8];
  const float* ln1_b     = (const float*)d_in[9];
  const float* ln2_w     = (const float*)d_in[10];
  const float* ln2_b     = (const float*)d_in[11];
  const float* slice_w   = (const float*)d_in[12];
  const float* slice_b   = (const float*)d_in[13];
  const float* q_w       = (const float*)d_in[14];
  const float* q_b       = (const float*)d_in[15];
  const float* k_w       = (const float*)d_in[16];
  const float* k_b       = (const float*)d_in[17];
  const float* v_w       = (const float*)d_in[18];
  const float* v_b       = (const float*)d_in[19];
  const float* o_w       = (const float*)d_in[20];
  const float* o_b       = (const float*)d_in[21];
  const float* beta_raw  = (const float*)d_in[22];
  const float* ffn1_w    = (const float*)d_in[23];
  const float* ffn1_b    = (const float*)d_in[24];
  const float* ffn2_w    = (const float*)d_in[25];
  const float* ffn2_b    = (const float*)d_in[26];
  const float* out_w     = (const float*)d_in[27];
  const float* out_b     = (const float*)d_in[28];
  const int*   adj       = (const int*)d_in[29];
  float* out = (float*)d_out;

  float* ws = (float*)d_ws;
  size_t off = 0;
  float* h        = ws + off; off += (size_t)BB*NN*WW;
  float* wts      = ws + off; off += (size_t)BB*NN*SS;
  float* mu_rstd  = ws + off; off += (size_t)BB*NN*2;
  float* sacc     = ws + off; off += (size_t)BB*SS*WW;   // zeroed per layer
  float* wsumb    = ws + off; off += (size_t)BB*SS;      // zeroed per layer
  float* gb       = ws + off; off += (size_t)BB*SS*SS;   // zeroed per layer
  float* so       = ws + off; off += (size_t)BB*SS*WW;
  float* so_out   = ws + off; off += (size_t)BB*SS*WW;
  short* w1tb     = (short*)(ws + off); off += (size_t)NL*WW*NF/2;  // bf16 W1^T swz
  short* w2tb     = (short*)(ws + off); off += (size_t)NL*WW*NF/2;  // bf16 W2 chunk-major swz
  short* wtsb     = (short*)(ws + off); off += (size_t)BB*NN*SS/2;  // bf16 wts

  hipLaunchKernelGGL(k_tr1, dim3(NF/32, WW/32, NL), dim3(256), 0, stream,
      ffn1_w, w1tb);
  hipLaunchKernelGGL(k_tr2, dim3(WW/32, NF/32, NL), dim3(256), 0, stream,
      ffn2_w, w2tb);

  hipLaunchKernelGGL(k_embed, dim3(BB*NN/16), dim3(256), 0, stream,
      fields, coords, t_norm, freq, omega, in_w, in_b, h);

  for (int l = 0; l < NL; l++){
    hipMemsetAsync(sacc, 0,
        (size_t)(BB*SS*WW + BB*SS + BB*SS*SS)*sizeof(float), stream);
    hipLaunchKernelGGL(k_lnw, dim3(BB*NN/16), dim3(256), 0, stream,
        h, ln1_w + l*WW, ln1_b + l*WW,
        slice_w + (size_t)l*WW*SS, slice_b + l*SS, wts, wtsb, mu_rstd);
    hipLaunchKernelGGL(k_slices, dim3(157, BB), dim3(256), 0, stream,
        h, wts, mu_rstd, ln1_w + l*WW, ln1_b + l*WW, sacc, wsumb);
    hipLaunchKernelGGL(k_gb2, dim3(GB_BLKS), dim3(256), 0, stream,
        wtsb, adj, adj_vals, gb);
    hipLaunchKernelGGL(k_attn, dim3(NH, BB), dim3(256), 0, stream,
        sacc, wsumb, gb, beta_raw, l,
        q_w + (size_t)l*WW*WW, q_b + l*WW,
        k_w + (size_t)l*WW*WW, k_b + l*WW,
        v_w + (size_t)l*WW*WW, v_b + l*WW,
        so);
    hipLaunchKernelGGL(k_oproj, dim3(4, BB), dim3(256), 0, stream,
        so, o_w + (size_t)l*WW*WW, o_b + l*WW, so_out);
    hipLaunchKernelGGL(k_ffn8, dim3((NN + FTM - 1)/FTM, BB), dim3(256), 0, stream,
        h, wts, so_out, ln2_w + l*WW, ln2_b + l*WW,
        w1tb + (size_t)l*WW*NF, ffn1_b + l*NF,
        w2tb + (size_t)l*WW*NF, ffn2_b + l*WW);
  }

  hipLaunchKernelGGL(k_out, dim3((BB*NN + 255)/256), dim3(256), 0, stream,
      h, out_w, out_b, out);
}